// Round 2
// baseline (453.785 us; speedup 1.0000x reference)
//
#include <hip/hip_runtime.h>
#include <stdint.h>
#include <stddef.h>

// AttentionGCNLayer: B=4, N=2048, D=256, E=3 edge types, H=2 heads, I=2 GCN iters.
// Outputs: out (4,2048,256) fp32 then graph_attention (2,4,2048,2048) fp32.
// R4: all GEMM kernels converted to double-buffered 2-phase pipelines
// (prefetch next K-tile into alternate LDS buffer BEFORE current compute;
// one barrier per K-step instead of two, load latency hidden under MFMA).
// k_softmax fp32 attn stores are nontemporal (537 MB never re-read; keeps
// bf16 attn LLC-resident for the two spmm passes).
// R4b: nontemporal stores use clang ext-vector type (floatx4), not HIP float4
// (builtin rejects class types).

typedef unsigned short bf16_t;
typedef __attribute__((ext_vector_type(4))) float floatx4;
typedef __attribute__((ext_vector_type(8))) __bf16 bf16x8;
typedef __attribute__((ext_vector_type(4))) unsigned short u16x4;

__device__ __forceinline__ bf16_t f2b(float f) {
  union { float f; uint32_t u; } v; v.f = f;
  uint32_t r = v.u + 0x7FFFu + ((v.u >> 16) & 1u);   // round-to-nearest-even
  return (bf16_t)(r >> 16);
}
__device__ __forceinline__ float h2f(uint16_t u) {
  union { uint16_t u; _Float16 h; } v; v.u = u; return (float)v.h;
}
__device__ __forceinline__ uint16_t f2h(float f) {
  union { uint16_t u; _Float16 h; } v; v.h = (_Float16)f; return v.u;
}

typedef __attribute__((address_space(1))) void gvoid_t;
typedef __attribute__((address_space(3))) void svoid_t;
__device__ __forceinline__ void gll16(const void* g, void* l) {
  __builtin_amdgcn_global_load_lds((gvoid_t*)(g), (svoid_t*)(l), 16, 0, 0);
}

// ===== XOR-swizzled BK=64 staging & fragment reads ==========================
// BK=64: row = 64 bf16 = 8 chunks of 8. phys_chunk = log_chunk ^ (row&7).
// Reads land 2-way per bank group (free, m136). Staging covers each row's full
// span (permuted within the row) so global coalescing is unaffected.

template <int NR>  // NR rows x 64 cols
__device__ __forceinline__ void stage64(const bf16_t* G, int ldg, bf16_t* L) {
  const int lane = threadIdx.x & 63, wave = threadIdx.x >> 6;
  const int li = lane >> 3, cp = lane & 7;
#pragma unroll
  for (int t = 0; t < NR / 32; ++t) {
    int base_r = wave * (NR / 4) + t * 8;        // wave-uniform
    int r = base_r + li;
    int cl = cp ^ (r & 7);
    gll16(G + (size_t)r * ldg + cl * 8, L + base_r * 64);
  }
}
__device__ __forceinline__ bf16x8 frag64(const bf16_t* L, int row, int j, int quad) {
  int c = ((j << 2) + quad) ^ (row & 7);
  return *(const bf16x8*)(L + (row << 6) + (c << 3));
}

// ===== 128x128 core, double-buffered 2-phase (BK=32) ========================
__device__ __forceinline__ bf16x8 lds_frag(const bf16_t* base, int row, int quad) {
  return *(const bf16x8*)(base + (row << 5) + (((quad + (row >> 1)) & 3) << 3));
}
// lA, lB each sized 2*4096 bf16 (16 KB each).
__device__ __forceinline__ void gemm_core(
    const bf16_t* __restrict__ A, int lda, int rowA0,
    const bf16_t* __restrict__ Bt, int ldb, int rowB0,
    int K, bf16_t* lA, bf16_t* lB, floatx4 acc[4][4])
{
  const int lane = threadIdx.x & 63;
  const int wave = threadIdx.x >> 6;
  const int l16  = lane & 15;
  const int quad = lane >> 4;
  const int wm = (wave >> 1) << 6;
  const int wn = (wave & 1) << 6;
  const int srow = (wave << 5) + (lane >> 2);
  const int scol = (((lane & 3) - (srow >> 1)) & 3) << 3;
  const bf16_t* gA0 = A + (size_t)(rowA0 + srow) * lda + scol;
  const bf16_t* gA1 = gA0 + (size_t)16 * lda;
  const bf16_t* gB0 = Bt + (size_t)(rowB0 + srow) * ldb + scol;
  const bf16_t* gB1 = gB0 + (size_t)16 * ldb;
  const int soff = (wave << 5) * 32;

  // prologue: stage K-step 0 into buffer 0
  gll16(gA0, lA + soff);
  gll16(gA1, lA + soff + 512);
  gll16(gB0, lB + soff);
  gll16(gB1, lB + soff + 512);
  __syncthreads();

  const int nk = K >> 5;
  int cur = 0;
  for (int t = 0; t < nk; ++t) {
    if (t + 1 < nk) {                            // prefetch next into other buf
      const int k1 = (t + 1) << 5;
      bf16_t* nA = lA + ((cur ^ 1) << 12);
      bf16_t* nB = lB + ((cur ^ 1) << 12);
      gll16(gA0 + k1, nA + soff);
      gll16(gA1 + k1, nA + soff + 512);
      gll16(gB0 + k1, nB + soff);
      gll16(gB1 + k1, nB + soff + 512);
    }
    const bf16_t* cA = lA + (cur << 12);
    const bf16_t* cB = lB + (cur << 12);
    bf16x8 af[4], bv[4];
#pragma unroll
    for (int mi = 0; mi < 4; ++mi) af[mi] = lds_frag(cA, wm + mi * 16 + l16, quad);
#pragma unroll
    for (int ni = 0; ni < 4; ++ni) bv[ni] = lds_frag(cB, wn + ni * 16 + l16, quad);
#pragma unroll
    for (int mi = 0; mi < 4; ++mi)
#pragma unroll
      for (int ni = 0; ni < 4; ++ni)
        acc[mi][ni] = __builtin_amdgcn_mfma_f32_16x16x32_bf16(af[mi], bv[ni], acc[mi][ni], 0, 0, 0);
    __syncthreads();                             // drains prefetch + read fence
    cur ^= 1;
  }
}

#define TILE_IDS \
  const int lane = threadIdx.x & 63; \
  const int wave = threadIdx.x >> 6; \
  const int l16  = lane & 15; \
  const int quad = lane >> 4; \
  const int wm = (wave >> 1) << 6; \
  const int wn = (wave & 1) << 6;

#define TILE_IDS64 \
  const int lane = threadIdx.x & 63; \
  const int wave = threadIdx.x >> 6; \
  const int l16  = lane & 15; \
  const int quad = lane >> 4; \
  const int wn = wave << 5;

#define ZERO44(acc) \
  { const floatx4 z4_ = {0.f, 0.f, 0.f, 0.f}; \
    for (int mi_ = 0; mi_ < 4; ++mi_) for (int ni_ = 0; ni_ < 4; ++ni_) acc[mi_][ni_] = z4_; }
#define ZERO42(acc) \
  { const floatx4 z4_ = {0.f, 0.f, 0.f, 0.f}; \
    for (int mi_ = 0; mi_ < 4; ++mi_) for (int ni_ = 0; ni_ < 2; ++ni_) acc[mi_][ni_] = z4_; }

// --------------------------------------------------------------------------
__global__ __launch_bounds__(256) void k_cast_x(const float* __restrict__ x,
                                                bf16_t* __restrict__ xb) {
  int i = blockIdx.x * 256 + threadIdx.x;
  float4 a = ((const float4*)x)[i * 2];
  float4 b = ((const float4*)x)[i * 2 + 1];
  bf16_t o[8] = { f2b(a.x), f2b(a.y), f2b(a.z), f2b(a.w),
                  f2b(b.x), f2b(b.y), f2b(b.z), f2b(b.w) };
  ((uint4*)xb)[i] = *(uint4*)o;
}

__global__ __launch_bounds__(256) void k_cast_w(
    const float* __restrict__ Wq, const float* __restrict__ Wk,
    const float* __restrict__ gW, const float* __restrict__ aW,
    bf16_t* __restrict__ WqkT, bf16_t* __restrict__ gWT, bf16_t* __restrict__ aWT) {
  int idx = blockIdx.x * 256 + threadIdx.x;
  if (idx < 393216) {                            // 6 * 65536
    int zz = idx >> 16, r = idx & 65535;
    int n = r >> 8, k = r & 255;
    const float* src = (zz < 3) ? (Wq + (size_t)zz * 65536) : (Wk + (size_t)(zz - 3) * 65536);
    WqkT[idx] = f2b(src[k * 256 + n]);
  } else if (idx < 524288) {                     // + 2 * 65536
    int t = idx - 393216;
    int i = t >> 16, r = t & 65535;
    int f = r >> 8, k = r & 255;
    gWT[t] = f2b(gW[(size_t)i * 65536 + k * 256 + f]);
  } else if (idx < 655360) {                     // + 131072
    int t = idx - 524288;
    int f = t >> 9, k = t & 511;
    aWT[t] = f2b(aW[k * 256 + f]);
  }
}

// Q/K projections -> concatenated-K layout qcat/kcat[b][h][n][e*128+kk].
__global__ __launch_bounds__(256) void k_gemm_proj(
    const bf16_t* __restrict__ xb, const bf16_t* __restrict__ WqkT,
    const float* __restrict__ bq, const float* __restrict__ bk,
    bf16_t* __restrict__ qcat, bf16_t* __restrict__ kcat) {
  __shared__ bf16_t lA[8192], lB[8192];          // 2 x 4096 double-buffer
  int z = blockIdx.z;
  int e = (z < 3) ? z : z - 3;
  const bf16_t* Wz = WqkT + (size_t)z * 65536;
  const float* bias = ((z < 3) ? bq : bk) + e * 256;
  bf16_t* dst = (z < 3) ? qcat : kcat;
  int bm0 = blockIdx.y * 128, bn0 = blockIdx.x * 128;
  floatx4 acc[4][4];
  ZERO44(acc);
  gemm_core(xb, 256, bm0, Wz, 256, bn0, 256, lA, lB, acc);
  TILE_IDS;
#pragma unroll
  for (int mi = 0; mi < 4; ++mi)
#pragma unroll
    for (int ni = 0; ni < 4; ++ni)
#pragma unroll
      for (int r = 0; r < 4; ++r) {
        int row = bm0 + wm + mi * 16 + quad * 4 + r;   // b*2048+n
        int col = bn0 + wn + ni * 16 + l16;            // h*128+kk
        int b = row >> 11, n = row & 2047;
        int h = col >> 7, kk = col & 127;
        float v = acc[mi][ni][r] + bias[col];
        dst[((size_t)((b * 2 + h) * 2048 + n)) * 384 + e * 128 + kk] = f2b(v);
      }
}

// Masked scores, 64x128 tile, BK=64, 6-step double-buffered 2-phase.
// 1-D grid 4096: z = i&7 (XCD affinity), t=i>>3: y=t&31 (rows), x=t>>5 (cols).
// Output: fp16 scaled scores into sc16 (aliases abf), -60000 for masked.
__global__ __launch_bounds__(256) void k_scores(
    const bf16_t* __restrict__ qcat, const bf16_t* __restrict__ kcat,
    const int* __restrict__ adj, uint16_t* __restrict__ sc16) {
  __shared__ bf16_t lA[2][64 * 64];              // 16 KB
  __shared__ bf16_t lB[2][128 * 64];             // 32 KB
  int i = blockIdx.x;
  int z = i & 7, t = i >> 3;
  int y = t & 31, x = t >> 5;
  int h = z >> 2, b = z & 3;
  const bf16_t* A  = qcat + (size_t)(b * 2 + h) * 2048 * 384;
  const bf16_t* Bt = kcat + (size_t)(b * 2 + h) * 2048 * 384;
  const int* adjb = adj + (size_t)b * 2048 * 2048;
  int bm0 = y * 64, bn0 = x * 128;
  TILE_IDS64;

  uint32_t adjv[4][2];
#pragma unroll
  for (int mi = 0; mi < 4; ++mi)
#pragma unroll
    for (int ni = 0; ni < 2; ++ni) {
      int col = bn0 + wn + ni * 16 + l16;
      uint32_t v = 0;
#pragma unroll
      for (int r = 0; r < 4; ++r) {
        int row = bm0 + mi * 16 + quad * 4 + r;
        v |= ((uint32_t)adjb[(size_t)row * 2048 + col] & 3u) << (r * 8);
      }
      adjv[mi][ni] = v;
    }

  const bf16_t* Ab = A + (size_t)bm0 * 384;
  const bf16_t* Bb = Bt + (size_t)bn0 * 384;

  stage64<64>(Ab, 384, lA[0]);                   // prologue: step 0 -> buf 0
  stage64<128>(Bb, 384, lB[0]);
  __syncthreads();

  floatx4 sel[4][2];
  floatx4 acc[4][2];
  ZERO42(sel);
  ZERO42(acc);
  int cur = 0;
  for (int s = 0; s < 6; ++s) {                  // s = e*2 + half
    if (s + 1 < 6) {                             // prefetch next 64-chunk
      int off = (s + 1) << 6;
      stage64<64>(Ab + off, 384, lA[cur ^ 1]);
      stage64<128>(Bb + off, 384, lB[cur ^ 1]);
    }
#pragma unroll
    for (int j = 0; j < 2; ++j) {
      bf16x8 af[4], bv[2];
#pragma unroll
      for (int mi = 0; mi < 4; ++mi) af[mi] = frag64(lA[cur], mi * 16 + l16, j, quad);
#pragma unroll
      for (int ni = 0; ni < 2; ++ni) bv[ni] = frag64(lB[cur], wn + ni * 16 + l16, j, quad);
#pragma unroll
      for (int mi = 0; mi < 4; ++mi)
#pragma unroll
        for (int ni = 0; ni < 2; ++ni)
          acc[mi][ni] = __builtin_amdgcn_mfma_f32_16x16x32_bf16(af[mi], bv[ni], acc[mi][ni], 0, 0, 0);
    }
    if (s & 1) {                                 // edge e complete: select
      int e = s >> 1;
#pragma unroll
      for (int mi = 0; mi < 4; ++mi)
#pragma unroll
        for (int ni = 0; ni < 2; ++ni) {
          uint32_t av = adjv[mi][ni];
#pragma unroll
          for (int r = 0; r < 4; ++r) {
            bool m = (((av >> (r * 8)) & 255u) == (uint32_t)(e + 1));
            sel[mi][ni][r] = m ? acc[mi][ni][r] : sel[mi][ni][r];
          }
        }
      ZERO42(acc);
    }
    __syncthreads();
    cur ^= 1;
  }
  const float scale = 0.08838834764831845f;      // 1/sqrt(dk=128)
#pragma unroll
  for (int mi = 0; mi < 4; ++mi)
#pragma unroll
    for (int ni = 0; ni < 2; ++ni)
#pragma unroll
      for (int r = 0; r < 4; ++r) {
        int row = bm0 + mi * 16 + quad * 4 + r;
        int col = bn0 + wn + ni * 16 + l16;
        uint32_t a = (adjv[mi][ni] >> (r * 8)) & 255u;
        float v = (a == 0u) ? -60000.0f : sel[mi][ni][r] * scale;
        sc16[((size_t)z * 2048 + row) * 2048 + col] = f2h(v);
      }
}

// Row softmax: reads fp16 scores from sb, writes fp32 attn to `attn` (streaming,
// nontemporal: never re-read) and bf16 attn IN-PLACE over sb.
__global__ __launch_bounds__(256) void k_softmax(uint16_t* sb, float* attn) {
  int row = blockIdx.x * 4 + (threadIdx.x >> 6);
  int lane = threadIdx.x & 63;
  uint16_t* p = sb + (size_t)row * 2048;
  float f[32];
  float mx = -3.4e38f;
#pragma unroll
  for (int j = 0; j < 4; ++j) {
    uint4 hv = ((const uint4*)p)[j * 64 + lane];
    const uint16_t* hu = (const uint16_t*)&hv;
#pragma unroll
    for (int q = 0; q < 8; ++q) {
      float v = h2f(hu[q]);
      f[j * 8 + q] = v;
      mx = fmaxf(mx, v);
    }
  }
#pragma unroll
  for (int off = 32; off; off >>= 1) mx = fmaxf(mx, __shfl_xor(mx, off));
  float s = 0.f;
#pragma unroll
  for (int k = 0; k < 32; ++k) { f[k] = __expf(f[k] - mx); s += f[k]; }
#pragma unroll
  for (int off = 32; off; off >>= 1) s += __shfl_xor(s, off);
  float inv = 1.0f / s;
  floatx4* ar = (floatx4*)(attn + (size_t)row * 2048);
#pragma unroll
  for (int j = 0; j < 4; ++j) {
    float o[8];
#pragma unroll
    for (int q = 0; q < 8; ++q) o[q] = f[j * 8 + q] * inv;
    __builtin_nontemporal_store(*(floatx4*)&o[0], ar + (j * 64 + lane) * 2 + 0);
    __builtin_nontemporal_store(*(floatx4*)&o[4], ar + (j * 64 + lane) * 2 + 1);
    uint16_t ob[8];
#pragma unroll
    for (int q = 0; q < 8; ++q) ob[q] = f2b(o[q]);
    ((uint4*)p)[j * 64 + lane] = *(uint4*)ob;    // bf16 over the fp16 slot
  }
}

// h1 = A @ Wt with TRANSPOSED bf16 write: CT[slice][256][2048], slice = row>>11.
__global__ __launch_bounds__(256) void k_gemm_bf16T(
    const bf16_t* __restrict__ A, const bf16_t* __restrict__ Wt,
    bf16_t* __restrict__ CT) {
  __shared__ bf16_t lA[8192], lB[8192];
  int bm0 = blockIdx.y * 128, bn0 = blockIdx.x * 128;
  floatx4 acc[4][4];
  ZERO44(acc);
  gemm_core(A, 256, bm0, Wt, 256, bn0, 256, lA, lB, acc);
  TILE_IDS;
#pragma unroll
  for (int mi = 0; mi < 4; ++mi)
#pragma unroll
    for (int ni = 0; ni < 4; ++ni) {
      int row0 = bm0 + wm + mi * 16 + quad * 4;
      int col  = bn0 + wn + ni * 16 + l16;
      int s = row0 >> 11, n = row0 & 2047;
      u16x4 v = { f2b(acc[mi][ni][0]), f2b(acc[mi][ni][1]),
                  f2b(acc[mi][ni][2]), f2b(acc[mi][ni][3]) };
      *(u16x4*)&CT[(size_t)s * 524288 + (size_t)col * 2048 + n] = v;
    }
}

// sum_nei = attn @ h1, 64x128 tile, BK=64 double-buffered 2-phase, XCD swizzle.
// Epilogue: x_new = x_old + relu(acc + gcn_b).
__global__ __launch_bounds__(256) void k_spmm(
    const bf16_t* __restrict__ abf, const bf16_t* __restrict__ h1T,
    long sBb, long sBh, const float* __restrict__ bias,
    const float* __restrict__ rin, long rib, long rih,
    float* __restrict__ rout,
    bf16_t* __restrict__ obf, long obb, long obh, int ldo) {
  __shared__ bf16_t lA[2][64 * 64];              // 16 KB
  __shared__ bf16_t lB[2][128 * 64];             // 32 KB
  int i = blockIdx.x;
  int z = i & 7, t = i >> 3;
  int x = t & 1, y = t >> 1;
  int h = z >> 2, b = z & 3;
  const bf16_t* A  = abf + (size_t)z * 2048 * 2048;
  const bf16_t* Bt = h1T + (size_t)b * sBb + (size_t)h * sBh;
  const float* rz  = rin + (size_t)b * rib + (size_t)h * rih;
  bf16_t* oz = obf + (size_t)b * obb + (size_t)h * obh;
  int bm0 = y * 64, bn0 = x * 128;
  TILE_IDS64;
  const bf16_t* Ab = A + (size_t)bm0 * 2048;
  const bf16_t* Bb = Bt + (size_t)bn0 * 2048;

  stage64<64>(Ab, 2048, lA[0]);                  // prologue: k=0 -> buf 0
  stage64<128>(Bb, 2048, lB[0]);
  __syncthreads();

  floatx4 acc[4][2];
  ZERO42(acc);
  int cur = 0;
  for (int kt = 0; kt < 32; ++kt) {
    if (kt + 1 < 32) {                           // prefetch next K-tile
      int k1 = (kt + 1) << 6;
      stage64<64>(Ab + k1, 2048, lA[cur ^ 1]);
      stage64<128>(Bb + k1, 2048, lB[cur ^ 1]);
    }
#pragma unroll
    for (int j = 0; j < 2; ++j) {
      bf16x8 af[4], bv[2];
#pragma unroll
      for (int mi = 0; mi < 4; ++mi) af[mi] = frag64(lA[cur], mi * 16 + l16, j, quad);
#pragma unroll
      for (int ni = 0; ni < 2; ++ni) bv[ni] = frag64(lB[cur], wn + ni * 16 + l16, j, quad);
#pragma unroll
      for (int mi = 0; mi < 4; ++mi)
#pragma unroll
        for (int ni = 0; ni < 2; ++ni)
          acc[mi][ni] = __builtin_amdgcn_mfma_f32_16x16x32_bf16(af[mi], bv[ni], acc[mi][ni], 0, 0, 0);
    }
    __syncthreads();
    cur ^= 1;
  }
#pragma unroll
  for (int mi = 0; mi < 4; ++mi)
#pragma unroll
    for (int ni = 0; ni < 2; ++ni)
#pragma unroll
      for (int r = 0; r < 4; ++r) {
        int row = bm0 + mi * 16 + quad * 4 + r;
        int col = bn0 + wn + ni * 16 + l16;
        float s = acc[mi][ni][r] + bias[col];
        float xn = rz[(size_t)row * 256 + col] + fmaxf(s, 0.f);
        if (rout) rout[((size_t)z * 2048 + row) * 256 + col] = xn;
        oz[(size_t)row * ldo + col] = f2b(xn);
      }
}

// Final: out = xcat(8192x512) @ aggW(512x256) + agg_b, fp32.
__global__ __launch_bounds__(256) void k_final(
    const bf16_t* __restrict__ xcat, const bf16_t* __restrict__ aWT,
    const float* __restrict__ ab, float* __restrict__ out) {
  __shared__ bf16_t lA[8192], lB[8192];
  int bm0 = blockIdx.y * 128, bn0 = blockIdx.x * 128;
  floatx4 acc[4][4];
  ZERO44(acc);
  gemm_core(xcat, 512, bm0, aWT, 512, bn0, 512, lA, lB, acc);
  TILE_IDS;
#pragma unroll
  for (int mi = 0; mi < 4; ++mi)
#pragma unroll
    for (int ni = 0; ni < 4; ++ni)
#pragma unroll
      for (int r = 0; r < 4; ++r) {
        int row = bm0 + wm + mi * 16 + quad * 4 + r;
        int col = bn0 + wn + ni * 16 + l16;
        out[(size_t)row * 256 + col] = acc[mi][ni][r] + ab[col];
      }
}

// ---------------------------------------------------------------------------
extern "C" void kernel_launch(void* const* d_in, const int* in_sizes, int n_in,
                              void* d_out, int out_size, void* d_ws, size_t ws_size,
                              hipStream_t stream) {
  const float* x   = (const float*)d_in[0];
  const int*   adj = (const int*)d_in[1];
  const float* Wq  = (const float*)d_in[2];
  const float* bq  = (const float*)d_in[3];
  const float* Wk  = (const float*)d_in[4];
  const float* bk  = (const float*)d_in[5];
  const float* gW  = (const float*)d_in[6];
  const float* gb  = (const float*)d_in[7];
  const float* aW  = (const float*)d_in[8];
  const float* ab  = (const float*)d_in[9];
  float* out = (float*)d_out;                    // (4,2048,256)
  float* sc  = out + 2097152;                    // graph_attention (2,4,2048,2048)

  char* w = (char*)d_ws;
  bf16_t* xb   = (bf16_t*)w; w += 4194304;       // 8192x256 bf16
  bf16_t* WqkT = (bf16_t*)w; w += 786432;        // 6x256x256
  bf16_t* gWT  = (bf16_t*)w; w += 262144;        // 2x256x256
  bf16_t* aWT  = (bf16_t*)w; w += 262144;        // 256x512
  bf16_t* qcat = (bf16_t*)w; w += 12582912;      // [b][h][2048][384]
  bf16_t* kcat = (bf16_t*)w; w += 12582912;
  bf16_t* abf  = (bf16_t*)w; w += 67108864;      // [h][b][2048][2048]: fp16 scores then bf16 attn
  bf16_t* h1T  = (bf16_t*)w; w += 4194304;       // [b][256][2048]
  float*  x1   = (float*)w;  w += 16777216;      // [h][b][2048][256] fp32
  bf16_t* x1b  = (bf16_t*)w; w += 8388608;       // [h][b][2048][256] bf16
  bf16_t* h1T1 = qcat;                           // alias (free after k_scores)
  bf16_t* xcat = kcat;                           // alias (free after k_scores)

  k_cast_x<<<1024, 256, 0, stream>>>(x, xb);
  k_cast_w<<<2560, 256, 0, stream>>>(Wq, Wk, gW, aW, WqkT, gWT, aWT);
  k_gemm_proj<<<dim3(2, 64, 6), 256, 0, stream>>>(xb, WqkT, bq, bk, qcat, kcat);
  k_scores<<<4096, 256, 0, stream>>>(qcat, kcat, adj, (uint16_t*)abf);
  k_softmax<<<4096, 256, 0, stream>>>((uint16_t*)abf, sc);
  // GCN iter 0 (h1 shared across heads since x0 identical); transposed write
  k_gemm_bf16T<<<dim3(2, 64, 1), 256, 0, stream>>>(xb, gWT, h1T);
  k_spmm<<<512, 256, 0, stream>>>(abf, h1T, 524288L, 0L, gb,
                                  x, 524288L, 0L, x1,
                                  x1b, 524288L, 2097152L, 256);
  // GCN iter 1 (per-head x)
  k_gemm_bf16T<<<dim3(2, 128, 1), 256, 0, stream>>>(x1b, gWT + 65536, h1T1);
  k_spmm<<<512, 256, 0, stream>>>(abf, h1T1, 524288L, 2097152L, gb + 256,
                                  x1, 524288L, 2097152L, nullptr,
                                  xcat, 1048576L, 256L, 512);
  // Final aggregation
  k_final<<<dim3(2, 64, 1), 256, 0, stream>>>(xcat, aWT, ab, out);
}

// Round 3
// 429.530 us; speedup vs baseline: 1.0565x; 1.0565x over previous
//
#include <hip/hip_runtime.h>
#include <stdint.h>
#include <stddef.h>

// AttentionGCNLayer: B=4, N=2048, D=256, E=3 edge types, H=2 heads, I=2 GCN iters.
// Outputs: out (4,2048,256) fp32 then graph_attention (2,4,2048,2048) fp32.
// R3: k_scores BK=128 (3 barrier rounds, XOR-swizzled LDS), fp16 scores aliased
// into abf (saves 200+ MB traffic), z->XCD swizzle for L2 locality.
// R5: revert R4's explicit double-buffering (regressed 9%: wave-level overlap
// already hides staging; doubled LDS halved occupancy). k_spmm BK 64->128
// (same stage128 pattern as k_scores: halves barrier drains, 2x MFMA per
// drain, same 48 KB footprint). k_softmax fp32 stores nontemporal.

typedef unsigned short bf16_t;
typedef __attribute__((ext_vector_type(4))) float floatx4;
typedef __attribute__((ext_vector_type(8))) __bf16 bf16x8;
typedef __attribute__((ext_vector_type(4))) unsigned short u16x4;

__device__ __forceinline__ bf16_t f2b(float f) {
  union { float f; uint32_t u; } v; v.f = f;
  uint32_t r = v.u + 0x7FFFu + ((v.u >> 16) & 1u);   // round-to-nearest-even
  return (bf16_t)(r >> 16);
}
__device__ __forceinline__ float h2f(uint16_t u) {
  union { uint16_t u; _Float16 h; } v; v.u = u; return (float)v.h;
}
__device__ __forceinline__ uint16_t f2h(float f) {
  union { uint16_t u; _Float16 h; } v; v.h = (_Float16)f; return v.u;
}

typedef __attribute__((address_space(1))) void gvoid_t;
typedef __attribute__((address_space(3))) void svoid_t;
__device__ __forceinline__ void gll16(const void* g, void* l) {
  __builtin_amdgcn_global_load_lds((gvoid_t*)(g), (svoid_t*)(l), 16, 0, 0);
}

// ===== XOR-swizzled wide-BK staging & fragment reads ========================
// BK=128: row = 128 bf16 = 16 chunks of 8. phys_chunk = log_chunk ^ (row&15).
// Reads land 2-way per bank group (free, m136). Staging covers each row's full
// span (permuted within the row) so global coalescing is unaffected.

template <int NR>  // NR rows x 128 cols; wave w stages rows [w*NR/4, (w+1)*NR/4)
__device__ __forceinline__ void stage128(const bf16_t* G, int ldg, bf16_t* L) {
  const int lane = threadIdx.x & 63, wave = threadIdx.x >> 6;
  const int li = lane >> 4, cp = lane & 15;
#pragma unroll
  for (int t = 0; t < NR / 16; ++t) {
    int base_r = wave * (NR / 4) + t * 4;        // wave-uniform
    int r = base_r + li;
    int cl = cp ^ (r & 15);
    gll16(G + (size_t)r * ldg + cl * 8, L + base_r * 128);
  }
}
__device__ __forceinline__ bf16x8 frag128(const bf16_t* L, int row, int j, int quad) {
  int c = ((j << 2) + quad) ^ (row & 15);
  return *(const bf16x8*)(L + (row << 7) + (c << 3));
}

// ===== R2 128x128 core (kept for proj / bf16T / final; verified) ============
__device__ __forceinline__ bf16x8 lds_frag(const bf16_t* base, int row, int quad) {
  return *(const bf16x8*)(base + (row << 5) + (((quad + (row >> 1)) & 3) << 3));
}
__device__ __forceinline__ void gemm_core(
    const bf16_t* __restrict__ A, int lda, int rowA0,
    const bf16_t* __restrict__ Bt, int ldb, int rowB0,
    int K, bf16_t* lA, bf16_t* lB, floatx4 acc[4][4])
{
  const int lane = threadIdx.x & 63;
  const int wave = threadIdx.x >> 6;
  const int l16  = lane & 15;
  const int quad = lane >> 4;
  const int wm = (wave >> 1) << 6;
  const int wn = (wave & 1) << 6;
  const int srow = (wave << 5) + (lane >> 2);
  const int scol = (((lane & 3) - (srow >> 1)) & 3) << 3;
  const bf16_t* gA0 = A + (size_t)(rowA0 + srow) * lda + scol;
  const bf16_t* gA1 = gA0 + (size_t)16 * lda;
  const bf16_t* gB0 = Bt + (size_t)(rowB0 + srow) * ldb + scol;
  const bf16_t* gB1 = gB0 + (size_t)16 * ldb;
  bf16_t* lA0 = lA + (wave << 5) * 32;
  bf16_t* lA1 = lA0 + 16 * 32;
  bf16_t* lB0 = lB + (wave << 5) * 32;
  bf16_t* lB1 = lB0 + 16 * 32;

  for (int k0 = 0; k0 < K; k0 += 32) {
    __syncthreads();
    gll16(gA0 + k0, lA0);
    gll16(gA1 + k0, lA1);
    gll16(gB0 + k0, lB0);
    gll16(gB1 + k0, lB1);
    __syncthreads();
    bf16x8 af[4], bv[4];
#pragma unroll
    for (int mi = 0; mi < 4; ++mi) af[mi] = lds_frag(lA, wm + mi * 16 + l16, quad);
#pragma unroll
    for (int ni = 0; ni < 4; ++ni) bv[ni] = lds_frag(lB, wn + ni * 16 + l16, quad);
#pragma unroll
    for (int mi = 0; mi < 4; ++mi)
#pragma unroll
      for (int ni = 0; ni < 4; ++ni)
        acc[mi][ni] = __builtin_amdgcn_mfma_f32_16x16x32_bf16(af[mi], bv[ni], acc[mi][ni], 0, 0, 0);
  }
}

#define TILE_IDS \
  const int lane = threadIdx.x & 63; \
  const int wave = threadIdx.x >> 6; \
  const int l16  = lane & 15; \
  const int quad = lane >> 4; \
  const int wm = (wave >> 1) << 6; \
  const int wn = (wave & 1) << 6;

#define TILE_IDS64 \
  const int lane = threadIdx.x & 63; \
  const int wave = threadIdx.x >> 6; \
  const int l16  = lane & 15; \
  const int quad = lane >> 4; \
  const int wn = wave << 5;

#define ZERO44(acc) \
  { const floatx4 z4_ = {0.f, 0.f, 0.f, 0.f}; \
    for (int mi_ = 0; mi_ < 4; ++mi_) for (int ni_ = 0; ni_ < 4; ++ni_) acc[mi_][ni_] = z4_; }
#define ZERO42(acc) \
  { const floatx4 z4_ = {0.f, 0.f, 0.f, 0.f}; \
    for (int mi_ = 0; mi_ < 4; ++mi_) for (int ni_ = 0; ni_ < 2; ++ni_) acc[mi_][ni_] = z4_; }

// --------------------------------------------------------------------------
__global__ __launch_bounds__(256) void k_cast_x(const float* __restrict__ x,
                                                bf16_t* __restrict__ xb) {
  int i = blockIdx.x * 256 + threadIdx.x;
  float4 a = ((const float4*)x)[i * 2];
  float4 b = ((const float4*)x)[i * 2 + 1];
  bf16_t o[8] = { f2b(a.x), f2b(a.y), f2b(a.z), f2b(a.w),
                  f2b(b.x), f2b(b.y), f2b(b.z), f2b(b.w) };
  ((uint4*)xb)[i] = *(uint4*)o;
}

__global__ __launch_bounds__(256) void k_cast_w(
    const float* __restrict__ Wq, const float* __restrict__ Wk,
    const float* __restrict__ gW, const float* __restrict__ aW,
    bf16_t* __restrict__ WqkT, bf16_t* __restrict__ gWT, bf16_t* __restrict__ aWT) {
  int idx = blockIdx.x * 256 + threadIdx.x;
  if (idx < 393216) {                            // 6 * 65536
    int zz = idx >> 16, r = idx & 65535;
    int n = r >> 8, k = r & 255;
    const float* src = (zz < 3) ? (Wq + (size_t)zz * 65536) : (Wk + (size_t)(zz - 3) * 65536);
    WqkT[idx] = f2b(src[k * 256 + n]);
  } else if (idx < 524288) {                     // + 2 * 65536
    int t = idx - 393216;
    int i = t >> 16, r = t & 65535;
    int f = r >> 8, k = r & 255;
    gWT[t] = f2b(gW[(size_t)i * 65536 + k * 256 + f]);
  } else if (idx < 655360) {                     // + 131072
    int t = idx - 524288;
    int f = t >> 9, k = t & 511;
    aWT[t] = f2b(aW[k * 256 + f]);
  }
}

// Q/K projections -> concatenated-K layout qcat/kcat[b][h][n][e*128+kk].
__global__ __launch_bounds__(256) void k_gemm_proj(
    const bf16_t* __restrict__ xb, const bf16_t* __restrict__ WqkT,
    const float* __restrict__ bq, const float* __restrict__ bk,
    bf16_t* __restrict__ qcat, bf16_t* __restrict__ kcat) {
  __shared__ bf16_t lA[4096], lB[4096];
  int z = blockIdx.z;
  int e = (z < 3) ? z : z - 3;
  const bf16_t* Wz = WqkT + (size_t)z * 65536;
  const float* bias = ((z < 3) ? bq : bk) + e * 256;
  bf16_t* dst = (z < 3) ? qcat : kcat;
  int bm0 = blockIdx.y * 128, bn0 = blockIdx.x * 128;
  floatx4 acc[4][4];
  ZERO44(acc);
  gemm_core(xb, 256, bm0, Wz, 256, bn0, 256, lA, lB, acc);
  TILE_IDS;
#pragma unroll
  for (int mi = 0; mi < 4; ++mi)
#pragma unroll
    for (int ni = 0; ni < 4; ++ni)
#pragma unroll
      for (int r = 0; r < 4; ++r) {
        int row = bm0 + wm + mi * 16 + quad * 4 + r;   // b*2048+n
        int col = bn0 + wn + ni * 16 + l16;            // h*128+kk
        int b = row >> 11, n = row & 2047;
        int h = col >> 7, kk = col & 127;
        float v = acc[mi][ni][r] + bias[col];
        dst[((size_t)((b * 2 + h) * 2048 + n)) * 384 + e * 128 + kk] = f2b(v);
      }
}

// Masked scores, 64x128 tile, BK=128 (one barrier round per e-chunk).
// 1-D grid 4096: z = i&7 (XCD affinity), t=i>>3: y=t&31 (rows), x=t>>5 (cols).
// Output: fp16 scaled scores into sc16 (aliases abf), -60000 for masked.
__global__ __launch_bounds__(256) void k_scores(
    const bf16_t* __restrict__ qcat, const bf16_t* __restrict__ kcat,
    const int* __restrict__ adj, uint16_t* __restrict__ sc16) {
  __shared__ bf16_t lA[64 * 128];                // 16 KB
  __shared__ bf16_t lB[128 * 128];               // 32 KB
  int i = blockIdx.x;
  int z = i & 7, t = i >> 3;
  int y = t & 31, x = t >> 5;
  int h = z >> 2, b = z & 3;
  const bf16_t* A  = qcat + (size_t)(b * 2 + h) * 2048 * 384;
  const bf16_t* Bt = kcat + (size_t)(b * 2 + h) * 2048 * 384;
  const int* adjb = adj + (size_t)b * 2048 * 2048;
  int bm0 = y * 64, bn0 = x * 128;
  TILE_IDS64;

  uint32_t adjv[4][2];
#pragma unroll
  for (int mi = 0; mi < 4; ++mi)
#pragma unroll
    for (int ni = 0; ni < 2; ++ni) {
      int col = bn0 + wn + ni * 16 + l16;
      uint32_t v = 0;
#pragma unroll
      for (int r = 0; r < 4; ++r) {
        int row = bm0 + mi * 16 + quad * 4 + r;
        v |= ((uint32_t)adjb[(size_t)row * 2048 + col] & 3u) << (r * 8);
      }
      adjv[mi][ni] = v;
    }

  floatx4 sel[4][2];
  ZERO42(sel);
  for (int e = 0; e < 3; ++e) {
    __syncthreads();                             // protect prev round's reads
    stage128<64>(A + (size_t)bm0 * 384 + e * 128, 384, lA);
    stage128<128>(Bt + (size_t)bn0 * 384 + e * 128, 384, lB);
    __syncthreads();
    floatx4 acc[4][2];
    ZERO42(acc);
#pragma unroll
    for (int j = 0; j < 4; ++j) {
      bf16x8 af[4], bv[2];
#pragma unroll
      for (int mi = 0; mi < 4; ++mi) af[mi] = frag128(lA, mi * 16 + l16, j, quad);
#pragma unroll
      for (int ni = 0; ni < 2; ++ni) bv[ni] = frag128(lB, wn + ni * 16 + l16, j, quad);
#pragma unroll
      for (int mi = 0; mi < 4; ++mi)
#pragma unroll
        for (int ni = 0; ni < 2; ++ni)
          acc[mi][ni] = __builtin_amdgcn_mfma_f32_16x16x32_bf16(af[mi], bv[ni], acc[mi][ni], 0, 0, 0);
    }
#pragma unroll
    for (int mi = 0; mi < 4; ++mi)
#pragma unroll
      for (int ni = 0; ni < 2; ++ni) {
        uint32_t av = adjv[mi][ni];
#pragma unroll
        for (int r = 0; r < 4; ++r) {
          bool m = (((av >> (r * 8)) & 255u) == (uint32_t)(e + 1));
          sel[mi][ni][r] = m ? acc[mi][ni][r] : sel[mi][ni][r];
        }
      }
  }
  const float scale = 0.08838834764831845f;      // 1/sqrt(dk=128)
#pragma unroll
  for (int mi = 0; mi < 4; ++mi)
#pragma unroll
    for (int ni = 0; ni < 2; ++ni)
#pragma unroll
      for (int r = 0; r < 4; ++r) {
        int row = bm0 + mi * 16 + quad * 4 + r;
        int col = bn0 + wn + ni * 16 + l16;
        uint32_t a = (adjv[mi][ni] >> (r * 8)) & 255u;
        float v = (a == 0u) ? -60000.0f : sel[mi][ni][r] * scale;
        sc16[((size_t)z * 2048 + row) * 2048 + col] = f2h(v);
      }
}

// Row softmax: reads fp16 scores from sb, writes fp32 attn to `attn`
// (nontemporal: 134 MB never re-read, keep LLC for the bf16 attn) and bf16
// attn IN-PLACE over sb (same addresses; full row in regs before stores).
__global__ __launch_bounds__(256) void k_softmax(uint16_t* sb, float* attn) {
  int row = blockIdx.x * 4 + (threadIdx.x >> 6);
  int lane = threadIdx.x & 63;
  uint16_t* p = sb + (size_t)row * 2048;
  float f[32];
  float mx = -3.4e38f;
#pragma unroll
  for (int j = 0; j < 4; ++j) {
    uint4 hv = ((const uint4*)p)[j * 64 + lane];
    const uint16_t* hu = (const uint16_t*)&hv;
#pragma unroll
    for (int q = 0; q < 8; ++q) {
      float v = h2f(hu[q]);
      f[j * 8 + q] = v;
      mx = fmaxf(mx, v);
    }
  }
#pragma unroll
  for (int off = 32; off; off >>= 1) mx = fmaxf(mx, __shfl_xor(mx, off));
  float s = 0.f;
#pragma unroll
  for (int k = 0; k < 32; ++k) { f[k] = __expf(f[k] - mx); s += f[k]; }
#pragma unroll
  for (int off = 32; off; off >>= 1) s += __shfl_xor(s, off);
  float inv = 1.0f / s;
  floatx4* ar = (floatx4*)(attn + (size_t)row * 2048);
#pragma unroll
  for (int j = 0; j < 4; ++j) {
    float o[8];
#pragma unroll
    for (int q = 0; q < 8; ++q) o[q] = f[j * 8 + q] * inv;
    __builtin_nontemporal_store(*(floatx4*)&o[0], ar + (j * 64 + lane) * 2 + 0);
    __builtin_nontemporal_store(*(floatx4*)&o[4], ar + (j * 64 + lane) * 2 + 1);
    uint16_t ob[8];
#pragma unroll
    for (int q = 0; q < 8; ++q) ob[q] = f2b(o[q]);
    ((uint4*)p)[j * 64 + lane] = *(uint4*)ob;    // bf16 over the fp16 slot
  }
}

// h1 = A @ Wt with TRANSPOSED bf16 write: CT[slice][256][2048], slice = row>>11.
__global__ __launch_bounds__(256) void k_gemm_bf16T(
    const bf16_t* __restrict__ A, const bf16_t* __restrict__ Wt,
    bf16_t* __restrict__ CT) {
  __shared__ bf16_t lA[4096], lB[4096];
  int bm0 = blockIdx.y * 128, bn0 = blockIdx.x * 128;
  floatx4 acc[4][4];
  ZERO44(acc);
  gemm_core(A, 256, bm0, Wt, 256, bn0, 256, lA, lB, acc);
  TILE_IDS;
#pragma unroll
  for (int mi = 0; mi < 4; ++mi)
#pragma unroll
    for (int ni = 0; ni < 4; ++ni) {
      int row0 = bm0 + wm + mi * 16 + quad * 4;
      int col  = bn0 + wn + ni * 16 + l16;
      int s = row0 >> 11, n = row0 & 2047;
      u16x4 v = { f2b(acc[mi][ni][0]), f2b(acc[mi][ni][1]),
                  f2b(acc[mi][ni][2]), f2b(acc[mi][ni][3]) };
      *(u16x4*)&CT[(size_t)s * 524288 + (size_t)col * 2048 + n] = v;
    }
}

// sum_nei = attn @ h1, 64x128 tile, BK=128 (16 barrier rounds), z->XCD swizzle.
// Epilogue: x_new = x_old + relu(acc + gcn_b).
__global__ __launch_bounds__(256) void k_spmm(
    const bf16_t* __restrict__ abf, const bf16_t* __restrict__ h1T,
    long sBb, long sBh, const float* __restrict__ bias,
    const float* __restrict__ rin, long rib, long rih,
    float* __restrict__ rout,
    bf16_t* __restrict__ obf, long obb, long obh, int ldo) {
  __shared__ bf16_t lA[64 * 128];                // 16 KB
  __shared__ bf16_t lB[128 * 128];               // 32 KB
  int i = blockIdx.x;
  int z = i & 7, t = i >> 3;
  int x = t & 1, y = t >> 1;
  int h = z >> 2, b = z & 3;
  const bf16_t* A  = abf + (size_t)z * 2048 * 2048;
  const bf16_t* Bt = h1T + (size_t)b * sBb + (size_t)h * sBh;
  const float* rz  = rin + (size_t)b * rib + (size_t)h * rih;
  bf16_t* oz = obf + (size_t)b * obb + (size_t)h * obh;
  int bm0 = y * 64, bn0 = x * 128;
  TILE_IDS64;
  const bf16_t* Ab = A + (size_t)bm0 * 2048;
  const bf16_t* Bb = Bt + (size_t)bn0 * 2048;
  floatx4 acc[4][2];
  ZERO42(acc);
  for (int k0 = 0; k0 < 2048; k0 += 128) {
    __syncthreads();
    stage128<64>(Ab + k0, 2048, lA);
    stage128<128>(Bb + k0, 2048, lB);
    __syncthreads();
#pragma unroll
    for (int j = 0; j < 4; ++j) {
      bf16x8 af[4], bv[2];
#pragma unroll
      for (int mi = 0; mi < 4; ++mi) af[mi] = frag128(lA, mi * 16 + l16, j, quad);
#pragma unroll
      for (int ni = 0; ni < 2; ++ni) bv[ni] = frag128(lB, wn + ni * 16 + l16, j, quad);
#pragma unroll
      for (int mi = 0; mi < 4; ++mi)
#pragma unroll
        for (int ni = 0; ni < 2; ++ni)
          acc[mi][ni] = __builtin_amdgcn_mfma_f32_16x16x32_bf16(af[mi], bv[ni], acc[mi][ni], 0, 0, 0);
    }
  }
#pragma unroll
  for (int mi = 0; mi < 4; ++mi)
#pragma unroll
    for (int ni = 0; ni < 2; ++ni)
#pragma unroll
      for (int r = 0; r < 4; ++r) {
        int row = bm0 + mi * 16 + quad * 4 + r;
        int col = bn0 + wn + ni * 16 + l16;
        float s = acc[mi][ni][r] + bias[col];
        float xn = rz[(size_t)row * 256 + col] + fmaxf(s, 0.f);
        if (rout) rout[((size_t)z * 2048 + row) * 256 + col] = xn;
        oz[(size_t)row * ldo + col] = f2b(xn);
      }
}

// Final: out = xcat(8192x512) @ aggW(512x256) + agg_b, fp32.
__global__ __launch_bounds__(256) void k_final(
    const bf16_t* __restrict__ xcat, const bf16_t* __restrict__ aWT,
    const float* __restrict__ ab, float* __restrict__ out) {
  __shared__ bf16_t lA[4096], lB[4096];
  int bm0 = blockIdx.y * 128, bn0 = blockIdx.x * 128;
  floatx4 acc[4][4];
  ZERO44(acc);
  gemm_core(xcat, 512, bm0, aWT, 512, bn0, 512, lA, lB, acc);
  TILE_IDS;
#pragma unroll
  for (int mi = 0; mi < 4; ++mi)
#pragma unroll
    for (int ni = 0; ni < 4; ++ni)
#pragma unroll
      for (int r = 0; r < 4; ++r) {
        int row = bm0 + wm + mi * 16 + quad * 4 + r;
        int col = bn0 + wn + ni * 16 + l16;
        out[(size_t)row * 256 + col] = acc[mi][ni][r] + ab[col];
      }
}

// ---------------------------------------------------------------------------
extern "C" void kernel_launch(void* const* d_in, const int* in_sizes, int n_in,
                              void* d_out, int out_size, void* d_ws, size_t ws_size,
                              hipStream_t stream) {
  const float* x   = (const float*)d_in[0];
  const int*   adj = (const int*)d_in[1];
  const float* Wq  = (const float*)d_in[2];
  const float* bq  = (const float*)d_in[3];
  const float* Wk  = (const float*)d_in[4];
  const float* bk  = (const float*)d_in[5];
  const float* gW  = (const float*)d_in[6];
  const float* gb  = (const float*)d_in[7];
  const float* aW  = (const float*)d_in[8];
  const float* ab  = (const float*)d_in[9];
  float* out = (float*)d_out;                    // (4,2048,256)
  float* sc  = out + 2097152;                    // graph_attention (2,4,2048,2048)

  char* w = (char*)d_ws;
  bf16_t* xb   = (bf16_t*)w; w += 4194304;       // 8192x256 bf16
  bf16_t* WqkT = (bf16_t*)w; w += 786432;        // 6x256x256
  bf16_t* gWT  = (bf16_t*)w; w += 262144;        // 2x256x256
  bf16_t* aWT  = (bf16_t*)w; w += 262144;        // 256x512
  bf16_t* qcat = (bf16_t*)w; w += 12582912;      // [b][h][2048][384]
  bf16_t* kcat = (bf16_t*)w; w += 12582912;
  bf16_t* abf  = (bf16_t*)w; w += 67108864;      // [h][b][2048][2048]: fp16 scores then bf16 attn
  bf16_t* h1T  = (bf16_t*)w; w += 4194304;       // [b][256][2048]
  float*  x1   = (float*)w;  w += 16777216;      // [h][b][2048][256] fp32
  bf16_t* x1b  = (bf16_t*)w; w += 8388608;       // [h][b][2048][256] bf16
  bf16_t* h1T1 = qcat;                           // alias (free after k_scores)
  bf16_t* xcat = kcat;                           // alias (free after k_scores)

  k_cast_x<<<1024, 256, 0, stream>>>(x, xb);
  k_cast_w<<<2560, 256, 0, stream>>>(Wq, Wk, gW, aW, WqkT, gWT, aWT);
  k_gemm_proj<<<dim3(2, 64, 6), 256, 0, stream>>>(xb, WqkT, bq, bk, qcat, kcat);
  k_scores<<<4096, 256, 0, stream>>>(qcat, kcat, adj, (uint16_t*)abf);
  k_softmax<<<4096, 256, 0, stream>>>((uint16_t*)abf, sc);
  // GCN iter 0 (h1 shared across heads since x0 identical); transposed write
  k_gemm_bf16T<<<dim3(2, 64, 1), 256, 0, stream>>>(xb, gWT, h1T);
  k_spmm<<<512, 256, 0, stream>>>(abf, h1T, 524288L, 0L, gb,
                                  x, 524288L, 0L, x1,
                                  x1b, 524288L, 2097152L, 256);
  // GCN iter 1 (per-head x)
  k_gemm_bf16T<<<dim3(2, 128, 1), 256, 0, stream>>>(x1b, gWT + 65536, h1T1);
  k_spmm<<<512, 256, 0, stream>>>(abf, h1T1, 524288L, 2097152L, gb + 256,
                                  x1, 524288L, 2097152L, nullptr,
                                  xcat, 1048576L, 256L, 512);
  // Final aggregation
  k_final<<<dim3(2, 64, 1), 256, 0, stream>>>(xcat, aWT, ab, out);
}

// Round 4
// 420.947 us; speedup vs baseline: 1.0780x; 1.0204x over previous
//
#include <hip/hip_runtime.h>
#include <stdint.h>
#include <stddef.h>

// AttentionGCNLayer: B=4, N=2048, D=256, E=3 edge types, H=2 heads, I=2 GCN iters.
// Outputs: out (4,2048,256) fp32 then graph_attention (2,4,2048,2048) fp32.
// R3 (414.7us measured): k_scores BK=128 swizzled, fp16 scores aliased in abf,
// z->XCD swizzle, spmm BK=64. R4/R5 (dbuf, spmm BK=128, NT stores) regressed
// and are fully reverted.
// R6: (a) k_scores computes BOTH heads per block (adj read once: -67 MB HBM),
// (b) cast_x+cast_w merged, (c) GCN-iter0 h1 GEMM merged into proj launch as
// z=6 (same grid shape; fills dispatch tail). 10 -> 8 launches.

typedef unsigned short bf16_t;
typedef __attribute__((ext_vector_type(4))) float floatx4;
typedef __attribute__((ext_vector_type(8))) __bf16 bf16x8;
typedef __attribute__((ext_vector_type(4))) unsigned short u16x4;

__device__ __forceinline__ bf16_t f2b(float f) {
  union { float f; uint32_t u; } v; v.f = f;
  uint32_t r = v.u + 0x7FFFu + ((v.u >> 16) & 1u);   // round-to-nearest-even
  return (bf16_t)(r >> 16);
}
__device__ __forceinline__ float h2f(uint16_t u) {
  union { uint16_t u; _Float16 h; } v; v.u = u; return (float)v.h;
}
__device__ __forceinline__ uint16_t f2h(float f) {
  union { uint16_t u; _Float16 h; } v; v.h = (_Float16)f; return v.u;
}

typedef __attribute__((address_space(1))) void gvoid_t;
typedef __attribute__((address_space(3))) void svoid_t;
__device__ __forceinline__ void gll16(const void* g, void* l) {
  __builtin_amdgcn_global_load_lds((gvoid_t*)(g), (svoid_t*)(l), 16, 0, 0);
}

// ===== XOR-swizzled wide-BK staging & fragment reads ========================
// BK=128: row = 128 bf16 = 16 chunks of 8. phys_chunk = log_chunk ^ (row&15).
// BK=64:  row = 64 bf16  =  8 chunks of 8. phys_chunk = log_chunk ^ (row&7).
// Reads land 2-way per bank group (free, m136). Staging covers each row's full
// span (permuted within the row) so global coalescing is unaffected.

template <int NR>  // NR rows x 128 cols; wave w stages rows [w*NR/4, (w+1)*NR/4)
__device__ __forceinline__ void stage128(const bf16_t* G, int ldg, bf16_t* L) {
  const int lane = threadIdx.x & 63, wave = threadIdx.x >> 6;
  const int li = lane >> 4, cp = lane & 15;
#pragma unroll
  for (int t = 0; t < NR / 16; ++t) {
    int base_r = wave * (NR / 4) + t * 4;        // wave-uniform
    int r = base_r + li;
    int cl = cp ^ (r & 15);
    gll16(G + (size_t)r * ldg + cl * 8, L + base_r * 128);
  }
}
template <int NR>  // NR rows x 64 cols
__device__ __forceinline__ void stage64(const bf16_t* G, int ldg, bf16_t* L) {
  const int lane = threadIdx.x & 63, wave = threadIdx.x >> 6;
  const int li = lane >> 3, cp = lane & 7;
#pragma unroll
  for (int t = 0; t < NR / 32; ++t) {
    int base_r = wave * (NR / 4) + t * 8;        // wave-uniform
    int r = base_r + li;
    int cl = cp ^ (r & 7);
    gll16(G + (size_t)r * ldg + cl * 8, L + base_r * 64);
  }
}
__device__ __forceinline__ bf16x8 frag128(const bf16_t* L, int row, int j, int quad) {
  int c = ((j << 2) + quad) ^ (row & 15);
  return *(const bf16x8*)(L + (row << 7) + (c << 3));
}
__device__ __forceinline__ bf16x8 frag64(const bf16_t* L, int row, int j, int quad) {
  int c = ((j << 2) + quad) ^ (row & 7);
  return *(const bf16x8*)(L + (row << 6) + (c << 3));
}

// ===== R2 128x128 core (verified at 414.7) ==================================
__device__ __forceinline__ bf16x8 lds_frag(const bf16_t* base, int row, int quad) {
  return *(const bf16x8*)(base + (row << 5) + (((quad + (row >> 1)) & 3) << 3));
}
__device__ __forceinline__ void gemm_core(
    const bf16_t* __restrict__ A, int lda, int rowA0,
    const bf16_t* __restrict__ Bt, int ldb, int rowB0,
    int K, bf16_t* lA, bf16_t* lB, floatx4 acc[4][4])
{
  const int lane = threadIdx.x & 63;
  const int wave = threadIdx.x >> 6;
  const int l16  = lane & 15;
  const int quad = lane >> 4;
  const int wm = (wave >> 1) << 6;
  const int wn = (wave & 1) << 6;
  const int srow = (wave << 5) + (lane >> 2);
  const int scol = (((lane & 3) - (srow >> 1)) & 3) << 3;
  const bf16_t* gA0 = A + (size_t)(rowA0 + srow) * lda + scol;
  const bf16_t* gA1 = gA0 + (size_t)16 * lda;
  const bf16_t* gB0 = Bt + (size_t)(rowB0 + srow) * ldb + scol;
  const bf16_t* gB1 = gB0 + (size_t)16 * ldb;
  bf16_t* lA0 = lA + (wave << 5) * 32;
  bf16_t* lA1 = lA0 + 16 * 32;
  bf16_t* lB0 = lB + (wave << 5) * 32;
  bf16_t* lB1 = lB0 + 16 * 32;

  for (int k0 = 0; k0 < K; k0 += 32) {
    __syncthreads();
    gll16(gA0 + k0, lA0);
    gll16(gA1 + k0, lA1);
    gll16(gB0 + k0, lB0);
    gll16(gB1 + k0, lB1);
    __syncthreads();
    bf16x8 af[4], bv[4];
#pragma unroll
    for (int mi = 0; mi < 4; ++mi) af[mi] = lds_frag(lA, wm + mi * 16 + l16, quad);
#pragma unroll
    for (int ni = 0; ni < 4; ++ni) bv[ni] = lds_frag(lB, wn + ni * 16 + l16, quad);
#pragma unroll
    for (int mi = 0; mi < 4; ++mi)
#pragma unroll
      for (int ni = 0; ni < 4; ++ni)
        acc[mi][ni] = __builtin_amdgcn_mfma_f32_16x16x32_bf16(af[mi], bv[ni], acc[mi][ni], 0, 0, 0);
  }
}

#define TILE_IDS \
  const int lane = threadIdx.x & 63; \
  const int wave = threadIdx.x >> 6; \
  const int l16  = lane & 15; \
  const int quad = lane >> 4; \
  const int wm = (wave >> 1) << 6; \
  const int wn = (wave & 1) << 6;

#define TILE_IDS64 \
  const int lane = threadIdx.x & 63; \
  const int wave = threadIdx.x >> 6; \
  const int l16  = lane & 15; \
  const int quad = lane >> 4; \
  const int wn = wave << 5;

#define ZERO44(acc) \
  { const floatx4 z4_ = {0.f, 0.f, 0.f, 0.f}; \
    for (int mi_ = 0; mi_ < 4; ++mi_) for (int ni_ = 0; ni_ < 4; ++ni_) acc[mi_][ni_] = z4_; }
#define ZERO42(acc) \
  { const floatx4 z4_ = {0.f, 0.f, 0.f, 0.f}; \
    for (int mi_ = 0; mi_ < 4; ++mi_) for (int ni_ = 0; ni_ < 2; ++ni_) acc[mi_][ni_] = z4_; }

// --------------------------------------------------------------------------
// Merged cast: x (262144 uint4-groups) then weights (655360 elems).
__global__ __launch_bounds__(256) void k_cast(
    const float* __restrict__ x,
    const float* __restrict__ Wq, const float* __restrict__ Wk,
    const float* __restrict__ gW, const float* __restrict__ aW,
    bf16_t* __restrict__ xb,
    bf16_t* __restrict__ WqkT, bf16_t* __restrict__ gWT, bf16_t* __restrict__ aWT) {
  int idx = blockIdx.x * 256 + threadIdx.x;
  if (idx < 262144) {                            // x: 8192*256/8 groups
    int i = idx;
    float4 a = ((const float4*)x)[i * 2];
    float4 b = ((const float4*)x)[i * 2 + 1];
    bf16_t o[8] = { f2b(a.x), f2b(a.y), f2b(a.z), f2b(a.w),
                    f2b(b.x), f2b(b.y), f2b(b.z), f2b(b.w) };
    ((uint4*)xb)[i] = *(uint4*)o;
    return;
  }
  int t0 = idx - 262144;
  if (t0 < 393216) {                             // 6 * 65536
    int zz = t0 >> 16, r = t0 & 65535;
    int n = r >> 8, k = r & 255;
    const float* src = (zz < 3) ? (Wq + (size_t)zz * 65536) : (Wk + (size_t)(zz - 3) * 65536);
    WqkT[t0] = f2b(src[k * 256 + n]);
  } else if (t0 < 524288) {                      // + 2 * 65536
    int t = t0 - 393216;
    int i = t >> 16, r = t & 65535;
    int f = r >> 8, k = r & 255;
    gWT[t] = f2b(gW[(size_t)i * 65536 + k * 256 + f]);
  } else if (t0 < 655360) {                      // + 131072
    int t = t0 - 524288;
    int f = t >> 9, k = t & 511;
    aWT[t] = f2b(aW[k * 256 + f]);
  }
}

// Q/K projections (z=0..5) -> qcat/kcat[b][h][n][e*128+kk];
// z=6: GCN iter-0 h1 = xb @ gWT[0] with transposed bf16 write into h1T.
__global__ __launch_bounds__(256) void k_gemm_proj(
    const bf16_t* __restrict__ xb, const bf16_t* __restrict__ WqkT,
    const bf16_t* __restrict__ gWT,
    const float* __restrict__ bq, const float* __restrict__ bk,
    bf16_t* __restrict__ qcat, bf16_t* __restrict__ kcat,
    bf16_t* __restrict__ h1T) {
  __shared__ bf16_t lA[4096], lB[4096];
  int z = blockIdx.z;
  const bf16_t* Wz = (z < 6) ? (WqkT + (size_t)z * 65536) : gWT;
  int bm0 = blockIdx.y * 128, bn0 = blockIdx.x * 128;
  floatx4 acc[4][4];
  ZERO44(acc);
  gemm_core(xb, 256, bm0, Wz, 256, bn0, 256, lA, lB, acc);
  TILE_IDS;
  if (z < 6) {
    int e = (z < 3) ? z : z - 3;
    const float* bias = ((z < 3) ? bq : bk) + e * 256;
    bf16_t* dst = (z < 3) ? qcat : kcat;
#pragma unroll
    for (int mi = 0; mi < 4; ++mi)
#pragma unroll
      for (int ni = 0; ni < 4; ++ni)
#pragma unroll
        for (int r = 0; r < 4; ++r) {
          int row = bm0 + wm + mi * 16 + quad * 4 + r;   // b*2048+n
          int col = bn0 + wn + ni * 16 + l16;            // h*128+kk
          int b = row >> 11, n = row & 2047;
          int h = col >> 7, kk = col & 127;
          float v = acc[mi][ni][r] + bias[col];
          dst[((size_t)((b * 2 + h) * 2048 + n)) * 384 + e * 128 + kk] = f2b(v);
        }
  } else {
#pragma unroll
    for (int mi = 0; mi < 4; ++mi)
#pragma unroll
      for (int ni = 0; ni < 4; ++ni) {
        int row0 = bm0 + wm + mi * 16 + quad * 4;
        int col  = bn0 + wn + ni * 16 + l16;
        int s = row0 >> 11, n = row0 & 2047;
        u16x4 v = { f2b(acc[mi][ni][0]), f2b(acc[mi][ni][1]),
                    f2b(acc[mi][ni][2]), f2b(acc[mi][ni][3]) };
        *(u16x4*)&h1T[(size_t)s * 524288 + (size_t)col * 2048 + n] = v;
      }
  }
}

// Masked scores, 64x128 tile, BK=128, BOTH heads per block (adj read once).
// 1-D grid 2048: b = i&3 (XCD affinity), t=i>>2: y=t&31 (rows), x=t>>5 (cols).
// Output: fp16 scaled scores into sc16 (aliases abf), -60000 for masked.
__global__ __launch_bounds__(256) void k_scores(
    const bf16_t* __restrict__ qcat, const bf16_t* __restrict__ kcat,
    const int* __restrict__ adj, uint16_t* __restrict__ sc16) {
  __shared__ bf16_t lA[64 * 128];                // 16 KB
  __shared__ bf16_t lB[128 * 128];               // 32 KB
  int i = blockIdx.x;
  int b = i & 3, t = i >> 2;
  int y = t & 31, x = t >> 5;
  const int* adjb = adj + (size_t)b * 2048 * 2048;
  int bm0 = y * 64, bn0 = x * 128;
  TILE_IDS64;

  uint32_t adjv[4][2];
#pragma unroll
  for (int mi = 0; mi < 4; ++mi)
#pragma unroll
    for (int ni = 0; ni < 2; ++ni) {
      int col = bn0 + wn + ni * 16 + l16;
      uint32_t v = 0;
#pragma unroll
      for (int r = 0; r < 4; ++r) {
        int row = bm0 + mi * 16 + quad * 4 + r;
        v |= ((uint32_t)adjb[(size_t)row * 2048 + col] & 3u) << (r * 8);
      }
      adjv[mi][ni] = v;
    }

  const float scale = 0.08838834764831845f;      // 1/sqrt(dk=128)
  for (int h = 0; h < 2; ++h) {
    const bf16_t* A  = qcat + (size_t)(b * 2 + h) * 2048 * 384;
    const bf16_t* Bt = kcat + (size_t)(b * 2 + h) * 2048 * 384;
    floatx4 sel[4][2];
    ZERO42(sel);
    for (int e = 0; e < 3; ++e) {
      __syncthreads();                           // protect prev round's reads
      stage128<64>(A + (size_t)bm0 * 384 + e * 128, 384, lA);
      stage128<128>(Bt + (size_t)bn0 * 384 + e * 128, 384, lB);
      __syncthreads();
      floatx4 acc[4][2];
      ZERO42(acc);
#pragma unroll
      for (int j = 0; j < 4; ++j) {
        bf16x8 af[4], bv[2];
#pragma unroll
        for (int mi = 0; mi < 4; ++mi) af[mi] = frag128(lA, mi * 16 + l16, j, quad);
#pragma unroll
        for (int ni = 0; ni < 2; ++ni) bv[ni] = frag128(lB, wn + ni * 16 + l16, j, quad);
#pragma unroll
        for (int mi = 0; mi < 4; ++mi)
#pragma unroll
          for (int ni = 0; ni < 2; ++ni)
            acc[mi][ni] = __builtin_amdgcn_mfma_f32_16x16x32_bf16(af[mi], bv[ni], acc[mi][ni], 0, 0, 0);
      }
#pragma unroll
      for (int mi = 0; mi < 4; ++mi)
#pragma unroll
        for (int ni = 0; ni < 2; ++ni) {
          uint32_t av = adjv[mi][ni];
#pragma unroll
          for (int r = 0; r < 4; ++r) {
            bool m = (((av >> (r * 8)) & 255u) == (uint32_t)(e + 1));
            sel[mi][ni][r] = m ? acc[mi][ni][r] : sel[mi][ni][r];
          }
        }
    }
    size_t zslice = (size_t)(h * 4 + b) * 2048;
#pragma unroll
    for (int mi = 0; mi < 4; ++mi)
#pragma unroll
      for (int ni = 0; ni < 2; ++ni)
#pragma unroll
        for (int r = 0; r < 4; ++r) {
          int row = bm0 + mi * 16 + quad * 4 + r;
          int col = bn0 + wn + ni * 16 + l16;
          uint32_t a = (adjv[mi][ni] >> (r * 8)) & 255u;
          float v = (a == 0u) ? -60000.0f : sel[mi][ni][r] * scale;
          sc16[(zslice + row) * 2048 + col] = f2h(v);
        }
  }
}

// Row softmax: reads fp16 scores from sb, writes fp32 attn to `attn` and bf16
// attn IN-PLACE over sb (same addresses; full row in regs before stores).
__global__ __launch_bounds__(256) void k_softmax(uint16_t* sb, float* attn) {
  int row = blockIdx.x * 4 + (threadIdx.x >> 6);
  int lane = threadIdx.x & 63;
  uint16_t* p = sb + (size_t)row * 2048;
  float f[32];
  float mx = -3.4e38f;
#pragma unroll
  for (int j = 0; j < 4; ++j) {
    uint4 hv = ((const uint4*)p)[j * 64 + lane];
    const uint16_t* hu = (const uint16_t*)&hv;
#pragma unroll
    for (int q = 0; q < 8; ++q) {
      float v = h2f(hu[q]);
      f[j * 8 + q] = v;
      mx = fmaxf(mx, v);
    }
  }
#pragma unroll
  for (int off = 32; off; off >>= 1) mx = fmaxf(mx, __shfl_xor(mx, off));
  float s = 0.f;
#pragma unroll
  for (int k = 0; k < 32; ++k) { f[k] = __expf(f[k] - mx); s += f[k]; }
#pragma unroll
  for (int off = 32; off; off >>= 1) s += __shfl_xor(s, off);
  float inv = 1.0f / s;
  float* ar = attn + (size_t)row * 2048;
#pragma unroll
  for (int j = 0; j < 4; ++j) {
    float o[8];
#pragma unroll
    for (int q = 0; q < 8; ++q) o[q] = f[j * 8 + q] * inv;
    ((float4*)ar)[(j * 64 + lane) * 2 + 0] = *(float4*)&o[0];
    ((float4*)ar)[(j * 64 + lane) * 2 + 1] = *(float4*)&o[4];
    uint16_t ob[8];
#pragma unroll
    for (int q = 0; q < 8; ++q) ob[q] = f2b(o[q]);
    ((uint4*)p)[j * 64 + lane] = *(uint4*)ob;    // bf16 over the fp16 slot
  }
}

// h1 = A @ Wt with TRANSPOSED bf16 write: CT[slice][256][2048], slice = row>>11.
__global__ __launch_bounds__(256) void k_gemm_bf16T(
    const bf16_t* __restrict__ A, const bf16_t* __restrict__ Wt,
    bf16_t* __restrict__ CT) {
  __shared__ bf16_t lA[4096], lB[4096];
  int bm0 = blockIdx.y * 128, bn0 = blockIdx.x * 128;
  floatx4 acc[4][4];
  ZERO44(acc);
  gemm_core(A, 256, bm0, Wt, 256, bn0, 256, lA, lB, acc);
  TILE_IDS;
#pragma unroll
  for (int mi = 0; mi < 4; ++mi)
#pragma unroll
    for (int ni = 0; ni < 4; ++ni) {
      int row0 = bm0 + wm + mi * 16 + quad * 4;
      int col  = bn0 + wn + ni * 16 + l16;
      int s = row0 >> 11, n = row0 & 2047;
      u16x4 v = { f2b(acc[mi][ni][0]), f2b(acc[mi][ni][1]),
                  f2b(acc[mi][ni][2]), f2b(acc[mi][ni][3]) };
      *(u16x4*)&CT[(size_t)s * 524288 + (size_t)col * 2048 + n] = v;
    }
}

// sum_nei = attn @ h1, 64x128 tile, BK=64, z->XCD swizzle.
// Epilogue: x_new = x_old + relu(acc + gcn_b).
__global__ __launch_bounds__(256) void k_spmm(
    const bf16_t* __restrict__ abf, const bf16_t* __restrict__ h1T,
    long sBb, long sBh, const float* __restrict__ bias,
    const float* __restrict__ rin, long rib, long rih,
    float* __restrict__ rout,
    bf16_t* __restrict__ obf, long obb, long obh, int ldo) {
  __shared__ bf16_t lA[64 * 64];                 // 8 KB
  __shared__ bf16_t lB[128 * 64];                // 16 KB
  int i = blockIdx.x;
  int z = i & 7, t = i >> 3;
  int x = t & 1, y = t >> 1;
  int h = z >> 2, b = z & 3;
  const bf16_t* A  = abf + (size_t)z * 2048 * 2048;
  const bf16_t* Bt = h1T + (size_t)b * sBb + (size_t)h * sBh;
  const float* rz  = rin + (size_t)b * rib + (size_t)h * rih;
  bf16_t* oz = obf + (size_t)b * obb + (size_t)h * obh;
  int bm0 = y * 64, bn0 = x * 128;
  TILE_IDS64;
  floatx4 acc[4][2];
  ZERO42(acc);
  for (int k0 = 0; k0 < 2048; k0 += 64) {
    __syncthreads();
    stage64<64>(A + (size_t)bm0 * 2048 + k0, 2048, lA);
    stage64<128>(Bt + (size_t)bn0 * 2048 + k0, 2048, lB);
    __syncthreads();
#pragma unroll
    for (int j = 0; j < 2; ++j) {
      bf16x8 af[4], bv[2];
#pragma unroll
      for (int mi = 0; mi < 4; ++mi) af[mi] = frag64(lA, mi * 16 + l16, j, quad);
#pragma unroll
      for (int ni = 0; ni < 2; ++ni) bv[ni] = frag64(lB, wn + ni * 16 + l16, j, quad);
#pragma unroll
      for (int mi = 0; mi < 4; ++mi)
#pragma unroll
        for (int ni = 0; ni < 2; ++ni)
          acc[mi][ni] = __builtin_amdgcn_mfma_f32_16x16x32_bf16(af[mi], bv[ni], acc[mi][ni], 0, 0, 0);
    }
  }
#pragma unroll
  for (int mi = 0; mi < 4; ++mi)
#pragma unroll
    for (int ni = 0; ni < 2; ++ni)
#pragma unroll
      for (int r = 0; r < 4; ++r) {
        int row = bm0 + mi * 16 + quad * 4 + r;
        int col = bn0 + wn + ni * 16 + l16;
        float s = acc[mi][ni][r] + bias[col];
        float xn = rz[(size_t)row * 256 + col] + fmaxf(s, 0.f);
        if (rout) rout[((size_t)z * 2048 + row) * 256 + col] = xn;
        oz[(size_t)row * ldo + col] = f2b(xn);
      }
}

// Final: out = xcat(8192x512) @ aggW(512x256) + agg_b, fp32.
__global__ __launch_bounds__(256) void k_final(
    const bf16_t* __restrict__ xcat, const bf16_t* __restrict__ aWT,
    const float* __restrict__ ab, float* __restrict__ out) {
  __shared__ bf16_t lA[4096], lB[4096];
  int bm0 = blockIdx.y * 128, bn0 = blockIdx.x * 128;
  floatx4 acc[4][4];
  ZERO44(acc);
  gemm_core(xcat, 512, bm0, aWT, 512, bn0, 512, lA, lB, acc);
  TILE_IDS;
#pragma unroll
  for (int mi = 0; mi < 4; ++mi)
#pragma unroll
    for (int ni = 0; ni < 4; ++ni)
#pragma unroll
      for (int r = 0; r < 4; ++r) {
        int row = bm0 + wm + mi * 16 + quad * 4 + r;
        int col = bn0 + wn + ni * 16 + l16;
        out[(size_t)row * 256 + col] = acc[mi][ni][r] + ab[col];
      }
}

// ---------------------------------------------------------------------------
extern "C" void kernel_launch(void* const* d_in, const int* in_sizes, int n_in,
                              void* d_out, int out_size, void* d_ws, size_t ws_size,
                              hipStream_t stream) {
  const float* x   = (const float*)d_in[0];
  const int*   adj = (const int*)d_in[1];
  const float* Wq  = (const float*)d_in[2];
  const float* bq  = (const float*)d_in[3];
  const float* Wk  = (const float*)d_in[4];
  const float* bk  = (const float*)d_in[5];
  const float* gW  = (const float*)d_in[6];
  const float* gb  = (const float*)d_in[7];
  const float* aW  = (const float*)d_in[8];
  const float* ab  = (const float*)d_in[9];
  float* out = (float*)d_out;                    // (4,2048,256)
  float* sc  = out + 2097152;                    // graph_attention (2,4,2048,2048)

  char* w = (char*)d_ws;
  bf16_t* xb   = (bf16_t*)w; w += 4194304;       // 8192x256 bf16
  bf16_t* WqkT = (bf16_t*)w; w += 786432;        // 6x256x256
  bf16_t* gWT  = (bf16_t*)w; w += 262144;        // 2x256x256
  bf16_t* aWT  = (bf16_t*)w; w += 262144;        // 256x512
  bf16_t* qcat = (bf16_t*)w; w += 12582912;      // [b][h][2048][384]
  bf16_t* kcat = (bf16_t*)w; w += 12582912;
  bf16_t* abf  = (bf16_t*)w; w += 67108864;      // [h][b][2048][2048]: fp16 scores then bf16 attn
  bf16_t* h1T  = (bf16_t*)w; w += 4194304;       // [b][256][2048]
  float*  x1   = (float*)w;  w += 16777216;      // [h][b][2048][256] fp32
  bf16_t* x1b  = (bf16_t*)w; w += 8388608;       // [h][b][2048][256] bf16
  bf16_t* h1T1 = qcat;                           // alias (free after k_scores)
  bf16_t* xcat = kcat;                           // alias (free after k_scores)

  k_cast<<<3584, 256, 0, stream>>>(x, Wq, Wk, gW, aW, xb, WqkT, gWT, aWT);
  // proj (z=0..5) + GCN iter-0 h1 transposed GEMM (z=6)
  k_gemm_proj<<<dim3(2, 64, 7), 256, 0, stream>>>(xb, WqkT, gWT, bq, bk,
                                                  qcat, kcat, h1T);
  k_scores<<<2048, 256, 0, stream>>>(qcat, kcat, adj, (uint16_t*)abf);
  k_softmax<<<4096, 256, 0, stream>>>((uint16_t*)abf, sc);
  k_spmm<<<512, 256, 0, stream>>>(abf, h1T, 524288L, 0L, gb,
                                  x, 524288L, 0L, x1,
                                  x1b, 524288L, 2097152L, 256);
  // GCN iter 1 (per-head x)
  k_gemm_bf16T<<<dim3(2, 128, 1), 256, 0, stream>>>(x1b, gWT + 65536, h1T1);
  k_spmm<<<512, 256, 0, stream>>>(abf, h1T1, 524288L, 2097152L, gb + 256,
                                  x1, 524288L, 2097152L, nullptr,
                                  xcat, 1048576L, 256L, 512);
  // Final aggregation
  k_final<<<dim3(2, 64, 1), 256, 0, stream>>>(xcat, aWT, ab, out);
}